// Round 1
// baseline (81.291 us; speedup 1.0000x reference)
//
#include <hip/hip_runtime.h>
#include <hip/hip_bf16.h>
#include <stdint.h>

#define B_N 65536
#define L_N 64
#define E_N 8
#define NS 64
#define MAXT (B_N/NS + E_N)   // 1032 max tiles

typedef __attribute__((ext_vector_type(4))) float f32x4;
typedef __attribute__((ext_vector_type(8))) short short8;

__device__ __forceinline__ short f2bf(float f){
  union { float f; unsigned u; } v; v.f = f;
  unsigned r = (v.u + 0x7fffu + ((v.u >> 16) & 1u)) >> 16;  // RNE
  return (short)r;
}

// ---------------- routing ----------------
__global__ void k_hist(const int* __restrict__ labels, unsigned* __restrict__ counts){
  __shared__ unsigned lc[8];
  if(threadIdx.x < 8) lc[threadIdx.x] = 0;
  __syncthreads();
  int i = blockIdx.x * blockDim.x + threadIdx.x;
  if(i < B_N) atomicAdd(&lc[labels[i] & 7], 1u);
  __syncthreads();
  if(threadIdx.x < 8 && lc[threadIdx.x]) atomicAdd(&counts[threadIdx.x], lc[threadIdx.x]);
}

__global__ void k_scan(const unsigned* __restrict__ counts, unsigned* __restrict__ cursor,
                       int* __restrict__ te, int* __restrict__ tb, int* __restrict__ tl){
  __shared__ int off[9], ts[9];
  if(threadIdx.x == 0){
    int o = 0, t = 0;
    for(int e=0;e<8;e++){
      off[e] = o; ts[e] = t;
      o += (int)counts[e];
      t += ((int)counts[e] + NS - 1) / NS;
    }
    off[8] = o; ts[8] = t;
    for(int e=0;e<8;e++) cursor[e] = (unsigned)off[e];
  }
  __syncthreads();
  for(int i = threadIdx.x; i < MAXT; i += blockDim.x){
    if(i < ts[8]){
      int e = 0;
      while(e < 7 && i >= ts[e+1]) e++;
      te[i] = e;
      tb[i] = off[e] + (i - ts[e]) * NS;
      tl[i] = off[e] + (int)counts[e];
    } else { te[i] = 0; tb[i] = 0; tl[i] = 0; }
  }
}

__global__ void k_scatter(const int* __restrict__ labels, unsigned* __restrict__ cursor,
                          int* __restrict__ perm){
  __shared__ unsigned lcnt[8], lbase[8];
  if(threadIdx.x < 8) lcnt[threadIdx.x] = 0;
  __syncthreads();
  int i = blockIdx.x * blockDim.x + threadIdx.x;
  int e = 0; unsigned r = 0;
  if(i < B_N){ e = labels[i] & 7; r = atomicAdd(&lcnt[e], 1u); }
  __syncthreads();
  if(threadIdx.x < 8 && lcnt[threadIdx.x])
    lbase[threadIdx.x] = atomicAdd(&cursor[threadIdx.x], lcnt[threadIdx.x]);
  __syncthreads();
  if(i < B_N) perm[lbase[e] + r] = i;
}

// ---------------- weight fragment prep ----------------
// frag layout per (expert, kstep): [t 0..15][lane 0..63][j 0..7] bf16 (16B/lane)
// A-frag element (lane l, j): out_f m = 16t + (l&15); k = 32s + 4(l>>4) + (j&3) + 16(j>>2)
__global__ void k_pw(const float* __restrict__ W0, const float* __restrict__ Wh,
                     short* __restrict__ wf0, short* __restrict__ wf1){
  int uid = blockIdx.x * blockDim.x + threadIdx.x;
  const int NU0 = 8*3*16*64;       // 24576
  const int NU1 = 2*8*8*16*64;     // 131072
  if(uid < NU0){
    int e = uid / 3072, r = uid % 3072;
    int s = r / 1024, r2 = r % 1024, t = r2 / 64, l = r2 % 64;
    int g = l >> 4, m = 16*t + (l & 15);
    short8 v;
    #pragma unroll
    for(int j=0;j<8;j++){
      int k = 32*s + 4*g + (j & 3) + 16*(j >> 2);
      float f = (k < 67) ? W0[(e*67 + k)*256 + m] : 0.f;
      v[j] = f2bf(f);
    }
    *(short8*)(wf0 + (size_t)uid * 8) = v;
  } else if(uid < NU0 + NU1){
    int u = uid - NU0;
    int lh = u / 65536, r = u % 65536;
    int e = r / 8192, r1 = r % 8192;
    int s = r1 / 1024, r2 = r1 % 1024, t = r2 / 64, l = r2 % 64;
    int g = l >> 4, m = 16*t + (l & 15);
    short8 v;
    #pragma unroll
    for(int j=0;j<8;j++){
      int k = 32*s + 4*g + (j & 3) + 16*(j >> 2);
      v[j] = f2bf(Wh[(((size_t)(lh*8 + e))*256 + k)*256 + m]);
    }
    *(short8*)(wf1 + (size_t)u * 8) = v;
  }
}

// ---------------- fused MoE MLP ----------------
__global__ __launch_bounds__(256) void k_mlp(
    const float* __restrict__ x, const float* __restrict__ eps,
    const float* __restrict__ mu_t, const float* __restrict__ lv_t,
    const float* __restrict__ b0, const float* __restrict__ bh,
    const float* __restrict__ Wo, const float* __restrict__ bo,
    const short* __restrict__ wf0, const short* __restrict__ wf1,
    const int* __restrict__ perm, const int* __restrict__ te,
    const int* __restrict__ tb, const int* __restrict__ tl,
    float* __restrict__ out)
{
  __shared__ short wbuf[2][16*64*8];                 // 2 x 16KB weight-frag staging
  __shared__ __align__(16) float bias_lds[3][256];
  __shared__ __align__(16) float wo_lds[256];

  const int tid = threadIdx.x;
  const int w = tid >> 6, lane = tid & 63;
  const int g = lane >> 4, col = lane & 15;
  const int bid = blockIdx.x;
  const int e = te[bid], base = tb[bid], lim = tl[bid];
  if(base >= lim) return;

  bias_lds[0][tid] = b0[e*256 + tid];
  bias_lds[1][tid] = bh[(0*8 + e)*256 + tid];
  bias_lds[2][tid] = bh[(1*8 + e)*256 + tid];
  wo_lds[tid] = Wo[e*256 + tid];

  const int pos = base + w*16 + col;
  const bool valid = pos < lim;
  const int sid = perm[valid ? pos : (lim - 1)];
  const float bo_e = bo[e];

  // ---- layer-0 B-fragments (x_in^T), built per-lane from gathered inputs ----
  short8 bx[3];
  #pragma unroll
  for(int s=0;s<3;s++){
    short8 v;
    #pragma unroll
    for(int jh=0;jh<2;jh++){
      #pragma unroll
      for(int q=0;q<4;q++){
        int k = 32*s + 4*g + 16*jh + q;
        float f = 0.f;
        if(k < 3) f = x[sid*3 + k];
        else if(k < 67){
          int zi = k - 3;
          f = mu_t[e*64 + zi] + eps[(size_t)sid*64 + zi] * __expf(0.5f * lv_t[e*64 + zi]);
        }
        v[jh*4 + q] = f2bf(f);
      }
    }
    bx[s] = v;
  }

  const short* w0e = wf0 + (size_t)e * (3*8192);
  const short* w1e = wf1 + (size_t)e * (8*8192);
  const short* w2e = wf1 + (size_t)(8 + e) * (8*8192);

  f32x4 acc[16];
  #pragma unroll
  for(int t=0;t<16;t++) acc[t] = (f32x4){0.f,0.f,0.f,0.f};
  short8 hb[8];

  // prologue: stage kstep 0 (each wave stages 4 of 16 fragment units)
  {
    #pragma unroll
    for(int q=0;q<4;q++){
      int u = w*4 + q;
      *(short8*)(&wbuf[0][u*512 + lane*8]) = *(const short8*)(w0e + u*512 + lane*8);
    }
  }

  // 19 ksteps total: 0..2 layer0 (K=96), 3..10 layer1, 11..18 layer2
  #pragma unroll
  for(int ks=0; ks<19; ks++){
    if(ks + 1 < 19){
      const short* src = (ks+1 < 3)  ? (w0e + (ks+1)*8192)
                       : (ks+1 < 11) ? (w1e + (ks+1-3)*8192)
                       :               (w2e + (ks+1-11)*8192);
      short* dst = &wbuf[(ks+1) & 1][0];
      #pragma unroll
      for(int q=0;q<4;q++){
        int u = w*4 + q;
        *(short8*)(dst + u*512 + lane*8) = *(const short8*)(src + u*512 + lane*8);
      }
    }
    __syncthreads();
    short8 bf = (ks < 3) ? bx[ks] : (ks < 11) ? hb[ks-3] : hb[ks-11];
    const short* buf = &wbuf[ks & 1][0];
    #pragma unroll
    for(int t=0;t<16;t++){
      short8 a = *(const short8*)(buf + t*512 + lane*8);
      acc[t] = __builtin_amdgcn_mfma_f32_16x16x32_bf16(a, bf, acc[t], 0, 0, 0);
    }
    if(ks == 2 || ks == 10){
      // layer epilogue: bias + relu, then repack accs as next layer's B-frags
      const float* bs = (ks==2) ? &bias_lds[0][0] : &bias_lds[1][0];
      #pragma unroll
      for(int t=0;t<16;t++){
        f32x4 b4 = *(const f32x4*)(bs + 16*t + 4*g);
        #pragma unroll
        for(int r=0;r<4;r++){
          float vv = acc[t][r] + b4[r];
          acc[t][r] = vv > 0.f ? vv : 0.f;
        }
      }
      #pragma unroll
      for(int s=0;s<8;s++){
        short8 h;
        #pragma unroll
        for(int r=0;r<4;r++){ h[r] = f2bf(acc[2*s][r]); h[4+r] = f2bf(acc[2*s+1][r]); }
        hb[s] = h;
      }
      #pragma unroll
      for(int t=0;t<16;t++) acc[t] = (f32x4){0.f,0.f,0.f,0.f};
    }
    __syncthreads();
  }

  // ---- output layer: bias+relu then dot with Wo, reduce across g-groups ----
  float dot = 0.f;
  #pragma unroll
  for(int t=0;t<16;t++){
    f32x4 b4 = *(const f32x4*)(&bias_lds[2][16*t + 4*g]);
    f32x4 w4 = *(const f32x4*)(&wo_lds[16*t + 4*g]);
    #pragma unroll
    for(int r=0;r<4;r++){
      float vv = acc[t][r] + b4[r];
      vv = vv > 0.f ? vv : 0.f;
      dot += vv * w4[r];
    }
  }
  dot += __shfl_xor(dot, 16, 64);
  dot += __shfl_xor(dot, 32, 64);
  if(g == 0 && valid) out[sid] = dot + bo_e;
}

// ---------------- KL ----------------
__global__ void k_kl(const float* __restrict__ mu_t, const float* __restrict__ lv_t,
                     const unsigned* __restrict__ counts, float* __restrict__ klout){
  __shared__ float fe[8];
  int t = threadIdx.x;
  if(t < 8){
    float s = 0.f;
    for(int i=0;i<64;i++){
      float m = mu_t[t*64+i], l = lv_t[t*64+i];
      s += 1.f + l - m*m - expf(l);
    }
    fe[t] = s;
  }
  __syncthreads();
  if(t == 0){
    float kl = 0.f;
    for(int e=0;e<8;e++) kl += fe[e] * (float)counts[e];
    klout[0] = -0.5f * kl / (float)B_N;
  }
}

extern "C" void kernel_launch(void* const* d_in, const int* in_sizes, int n_in,
                              void* d_out, int out_size, void* d_ws, size_t ws_size,
                              hipStream_t stream){
  (void)in_sizes; (void)n_in; (void)out_size; (void)ws_size;
  const float* x   = (const float*)d_in[0];
  const int*   lab = (const int*)d_in[1];
  const float* eps = (const float*)d_in[2];
  const float* mu  = (const float*)d_in[3];
  const float* lv  = (const float*)d_in[4];
  const float* W0  = (const float*)d_in[5];
  const float* b0  = (const float*)d_in[6];
  const float* Wh  = (const float*)d_in[7];
  const float* bh  = (const float*)d_in[8];
  const float* Wo  = (const float*)d_in[9];
  const float* bo  = (const float*)d_in[10];
  float* out = (float*)d_out;

  char* ws = (char*)d_ws;
  unsigned* counts = (unsigned*)(ws + 0);
  unsigned* cursor = (unsigned*)(ws + 32);
  int* te   = (int*)(ws + 128);
  int* tb   = (int*)(ws + 128 + 4*MAXT);
  int* tl   = (int*)(ws + 128 + 8*MAXT);
  int* perm = (int*)(ws + 12544);
  short* wf0 = (short*)(ws + 275456);   // 8 experts x 3 ksteps x 16KB
  short* wf1 = (short*)(ws + 668672);   // 2 layers x 8 experts x 8 ksteps x 16KB

  hipMemsetAsync(ws, 0, 64, stream);  // counts + cursor
  k_hist<<<256, 256, 0, stream>>>(lab, counts);
  k_scan<<<1, 256, 0, stream>>>(counts, cursor, te, tb, tl);
  k_scatter<<<256, 256, 0, stream>>>(lab, cursor, perm);
  k_pw<<<(24576 + 131072 + 255)/256, 256, 0, stream>>>(W0, Wh, wf0, wf1);
  k_mlp<<<MAXT, 256, 0, stream>>>(x, eps, mu, lv, b0, bh, Wo, bo,
                                  wf0, wf1, perm, te, tb, tl, out);
  k_kl<<<1, 64, 0, stream>>>(mu, lv, counts, out + B_N);
}